// Round 2
// baseline (416.233 us; speedup 1.0000x reference)
//
#include <hip/hip_runtime.h>
#include <hip/hip_cooperative_groups.h>

namespace cg = cooperative_groups;

// Problem constants
#define NB 64
#define NP 500
#define NC 128
#define NH 256
#define EPS_BN 1e-5f

// Edge-list geometry: 64 batches x 8 j-tiles, cap 1024 edges/segment
#define SEGS 8
#define CAPE 1024

// ws layout (float/int words)
#define EDGE_OFF 0
#define EDGE_WORDS (NB * SEGS * CAPE)            // 524288
#define CNT_OFF (EDGE_OFF + EDGE_WORDS)          // 512 words
#define CT_OFF (CNT_OFF + 512)                   // c matrix, feature-major [256][64]
#define H1_OFF (CT_OFF + NH * NB)
#define H2_OFF (H1_OFF + NH * NB)

// Output layout: tc[64] | tsys[64] | l2_points[4096000] | correlation[8192]
#define OUT_PTS_OFF 128
#define OUT_CORR_OFF 4096128

#define COPY_BLKS 1024
#define TOTAL_F4 1024000  // 4,096,000 floats / 4

// ---------------------------------------------------------------------------
// K1: pair scan (blocks 0..511) + per-batch misc (512..575) + FULL copy
// ---------------------------------------------------------------------------
__global__ __launch_bounds__(256) void k1_scan_misc_copy(
    const float* __restrict__ xyz,    // [B,3,N]
    const float* __restrict__ temp,   // [B,1,N]
    const float* __restrict__ l3,     // [B,C]
    const float* __restrict__ b4,     // [1] fc_lt4_b
    const float* __restrict__ pts,    // [B,C,N] l2_points
    float* __restrict__ out,
    float* __restrict__ ws) {
  const int blk = blockIdx.x;
  const int tid = threadIdx.x;

  if (blk < 512) {
    // -------- pair scan: batch b, j-tile jt, strictly upper (i<j) ---------
    const int b = blk >> 3;
    const int jt = blk & 7;
    __shared__ float4 pt[NP];  // x,y,z,s
    __shared__ int lcnt;
    if (tid == 0) lcnt = 0;
    const float* xr = xyz + b * 1500;
    for (int idx = tid; idx < NP; idx += 256) {
      float x = xr[idx], y = xr[500 + idx], z = xr[1000 + idx];
      float s = x * x + y * y + z * z;  // match ref jnp.sum(point*point)
      pt[idx] = make_float4(x, y, z, s);
    }
    __syncthreads();

    const int j0 = jt * 63;
    const int j1 = (j0 + 63 < NP) ? j0 + 63 : NP;
    const int i0 = tid;
    const int i1 = tid + 256;
    float4 p0 = pt[i0];
    float4 p1 = (i1 < NP) ? pt[i1] : make_float4(0.f, 0.f, 0.f, 0.f);
    int* eseg = (int*)ws + EDGE_OFF + (b * SEGS + jt) * CAPE;

    for (int j = j0; j < j1; ++j) {
      float4 q = pt[j];  // wave-uniform -> LDS broadcast
      if (i0 < j) {
        float dot = p0.x * q.x + p0.y * q.y + p0.z * q.z;
        float sq = p0.w + q.w - 2.f * dot;
        float d = sqrtf(fabsf(sq));
        if (d > 0.19f && d < 0.21f) {
          int e = atomicAdd(&lcnt, 1);
          if (e < CAPE) eseg[e] = (i0 << 16) | j;
        }
      }
      if (i1 < j) {
        float dot = p1.x * q.x + p1.y * q.y + p1.z * q.z;
        float sq = p1.w + q.w - 2.f * dot;
        float d = sqrtf(fabsf(sq));
        if (d > 0.19f && d < 0.21f) {
          int e = atomicAdd(&lcnt, 1);
          if (e < CAPE) eseg[e] = (i1 << 16) | j;
        }
      }
    }
    __syncthreads();
    if (tid == 0) {
      int c = lcnt < CAPE ? lcnt : CAPE;
      ((int*)ws)[CNT_OFF + b * SEGS + jt] = c;
    }
  } else if (blk < 576) {
    // -------- misc per batch: tsys, cT sa4 rows, tc bias init -------------
    const int b = blk - 512;
    float sum = 0.f;
    for (int i = tid; i < NP; i += 256) sum += temp[b * NP + i];
    for (int off = 32; off; off >>= 1) sum += __shfl_xor(sum, off);
    __shared__ float wsum[4];
    if ((tid & 63) == 0) wsum[tid >> 6] = sum;
    __syncthreads();
    if (tid == 0)
      out[64 + b] = (wsum[0] + wsum[1] + wsum[2] + wsum[3]) * (1.f / 500.f);
    if (tid < 128) ws[CT_OFF + (128 + tid) * 64 + b] = l3[b * NC + tid];
    if (tid == 0) out[b] = b4[0];  // tc starts at bias; K2 layer-3 atomicAdds
  } else {
    // -------- full copy of l2_points -> out ------------------------------
    const int cb = blk - 576;
    const float4* src = (const float4*)pts;
    float4* dst = (float4*)(out + OUT_PTS_OFF);
    for (int idx = cb * 256 + tid; idx < TOTAL_F4; idx += COPY_BLKS * 256)
      dst[idx] = src[idx];
  }
}

// ---------------------------------------------------------------------------
// K2 (cooperative, 512 blocks x 256): correlation then 4 fused MLP layers
// with grid.sync() between stages. BN is over the 64-batch dim -> fully
// block-local (one block owns one output feature for all 64 batches).
// ---------------------------------------------------------------------------
struct P2 {
  const float* data;  // l2_points [B,C,N]
  const float* W0; const float* B0; const float* G0; const float* E0;
  const float* W1; const float* B1; const float* G1; const float* E1;
  const float* W2; const float* B2; const float* G2; const float* E2;
  const float* W3; const float* B3; const float* G3; const float* E3;
  const float* w4;
  float* out;
  float* ws;
};

__global__ __launch_bounds__(256) void k2_mega(P2 p) {
  cg::grid_group grid = cg::this_grid();
  const int blk = blockIdx.x;
  const int tid = threadIdx.x;
  float* ws = p.ws;

  __shared__ float dT[NP * 20];  // [j][c] 16 channels, stride 20
  __shared__ float corrp[16];
  __shared__ float part[4][64];

  // ---------------- phase A: correlation (all 512 blocks) ----------------
  {
    const int b = blk >> 3;
    const int c0 = (blk & 7) * 16;
    if (tid < 16) corrp[tid] = 0.f;

    const float4* in4 = (const float4*)(p.data + (size_t)b * 64000 + c0 * 500);
    for (int idx = tid; idx < 2000; idx += 256) {
      float4 v = in4[idx];
      int c = idx / 125;
      int j = (idx - c * 125) * 4;
      dT[(j + 0) * 20 + c] = v.x;
      dT[(j + 1) * 20 + c] = v.y;
      dT[(j + 2) * 20 + c] = v.z;
      dT[(j + 3) * 20 + c] = v.w;
    }
    __syncthreads();

    const int quad = tid & 3;
    const int slot = tid >> 2;
    float4 acc = make_float4(0.f, 0.f, 0.f, 0.f);
    const int* cnts = (const int*)ws + CNT_OFF + b * SEGS;
    int Etot = 0;
    for (int seg = 0; seg < SEGS; ++seg) {
      int E = cnts[seg];
      Etot += E;
      const int* eseg = (const int*)ws + EDGE_OFF + (b * SEGS + seg) * CAPE;
      for (int e = slot; e < E; e += 64) {
        int ij = eseg[e];
        int i = ij >> 16, j = ij & 0xffff;
        const float4 a = *(const float4*)(dT + i * 20 + quad * 4);
        const float4 c4 = *(const float4*)(dT + j * 20 + quad * 4);
        acc.x += a.x * c4.x;
        acc.y += a.y * c4.y;
        acc.z += a.z * c4.z;
        acc.w += a.w * c4.w;
      }
    }
    for (int off = 4; off < 64; off <<= 1) {
      acc.x += __shfl_xor(acc.x, off);
      acc.y += __shfl_xor(acc.y, off);
      acc.z += __shfl_xor(acc.z, off);
      acc.w += __shfl_xor(acc.w, off);
    }
    if ((tid & 63) < 4) {
      atomicAdd(&corrp[quad * 4 + 0], acc.x);
      atomicAdd(&corrp[quad * 4 + 1], acc.y);
      atomicAdd(&corrp[quad * 4 + 2], acc.z);
      atomicAdd(&corrp[quad * 4 + 3], acc.w);
    }
    __syncthreads();
    if (tid < 16) {
      // mask symmetric: ordered count = 2E, ordered sum = 2 * upper sum
      float denom = fmaxf(2.f * (float)Etot, 1.f);
      float v = 2.f * corrp[tid] / denom;
      p.out[OUT_CORR_OFF + b * NC + c0 + tid] = v;
      ws[CT_OFF + (c0 + tid) * 64 + b] = v;
    }
  }

  // ---------------- phase B: 4 MLP layers, grid.sync between -------------
  float* cT = ws + CT_OFF;
  float* hA = ws + H1_OFF;
  float* hB = ws + H2_OFF;
  const float* Ws[4] = {p.W0, p.W1, p.W2, p.W3};
  const float* Bs[4] = {p.B0, p.B1, p.B2, p.B3};
  const float* Gs[4] = {p.G0, p.G1, p.G2, p.G3};
  const float* Es[4] = {p.E0, p.E1, p.E2, p.E3};
  const float* xs[4] = {cT, hA, hB, hA};
  float* ys[4] = {hA, hB, hA, nullptr};

  for (int l = 0; l < 4; ++l) {
    grid.sync();
    if (blk < 256) {
      const int o = blk;
      const int b = tid & 63;
      const int w = tid >> 6;
      const float* wr = Ws[l] + o * NH + w * 64;
      const float* xp = xs[l] + (w * 64) * 64 + b;
      float acc = 0.f;
#pragma unroll
      for (int i = 0; i < 64; ++i) acc += xp[i * 64] * wr[i];
      part[w][b] = acc;
      __syncthreads();
      if (w == 0) {
        float t = part[0][b] + part[1][b] + part[2][b] + part[3][b] + Bs[l][o];
        float s1 = t;
        for (int off = 32; off; off >>= 1) s1 += __shfl_xor(s1, off);
        float m = s1 * (1.f / 64.f);
        float d = t - m;
        float s2 = d * d;
        for (int off = 32; off; off >>= 1) s2 += __shfl_xor(s2, off);
        float var = s2 * (1.f / 64.f);
        float h = Gs[l][o] * d * rsqrtf(var + EPS_BN) + Es[l][o];
        h = fmaxf(h, 0.f);
        if (l == 3) {
          atomicAdd(&p.out[b], p.w4[o] * h);
        } else {
          ys[l][o * 64 + b] = h;
        }
      }
    }
  }
}

extern "C" void kernel_launch(void* const* d_in, const int* in_sizes, int n_in,
                              void* d_out, int out_size, void* d_ws,
                              size_t ws_size, hipStream_t stream) {
  const float* xyz = (const float*)d_in[0];
  const float* pts = (const float*)d_in[1];
  const float* l3 = (const float*)d_in[2];
  const float* temp = (const float*)d_in[3];

  float* out = (float*)d_out;
  float* ws = (float*)d_ws;

  k1_scan_misc_copy<<<576 + COPY_BLKS, 256, 0, stream>>>(
      xyz, temp, l3, (const float*)d_in[21], pts, out, ws);

  P2 p;
  p.data = pts;
  p.W0 = (const float*)d_in[4];  p.B0 = (const float*)d_in[5];
  p.G0 = (const float*)d_in[6];  p.E0 = (const float*)d_in[7];
  p.W1 = (const float*)d_in[8];  p.B1 = (const float*)d_in[9];
  p.G1 = (const float*)d_in[10]; p.E1 = (const float*)d_in[11];
  p.W2 = (const float*)d_in[12]; p.B2 = (const float*)d_in[13];
  p.G2 = (const float*)d_in[14]; p.E2 = (const float*)d_in[15];
  p.W3 = (const float*)d_in[16]; p.B3 = (const float*)d_in[17];
  p.G3 = (const float*)d_in[18]; p.E3 = (const float*)d_in[19];
  p.w4 = (const float*)d_in[20];
  p.out = out;
  p.ws = ws;

  void* args[] = {&p};
  hipLaunchCooperativeKernel(reinterpret_cast<void*>(k2_mega), dim3(512),
                             dim3(256), args, 0, stream);
}

// Round 3
// 232.722 us; speedup vs baseline: 1.7885x; 1.7885x over previous
//
#include <hip/hip_runtime.h>

// Problem constants
#define NB 64
#define NP 500
#define NC 128
#define NH 256
#define EPS_BN 1e-5f

// Edge-list geometry: 64 batches x 4 j-segments (125 j each), cap 2048
#define SEGS 4
#define CAPE 2048
#define JSEG 125

// ws word layout
#define EDGE_OFF 0
#define EDGE_WORDS (NB * SEGS * CAPE)        // 524288
#define CNT_OFF EDGE_WORDS                   // 256 words
#define BAR_OFF (CNT_OFF + 256)              // 1 word (padded to 64)
#define CT_OFF (BAR_OFF + 64)                // c matrix, feature-major [256][64]
#define H1_OFF (CT_OFF + NH * NB)
#define H2_OFF (H1_OFF + NH * NB)

// Output layout: tc[64] | tsys[64] | l2_points[4096000] | correlation[8192]
#define OUT_PTS_OFF 128
#define OUT_CORR_OFF 4096128

struct Params {
  const float* xyz;   // [B,3,N]
  const float* data;  // [B,C,N] l2_points
  const float* l3;    // [B,C]
  const float* temp;  // [B,1,N]
  const float* W0; const float* B0; const float* G0; const float* E0;
  const float* W1; const float* B1; const float* G1; const float* E1;
  const float* W2; const float* B2; const float* G2; const float* E2;
  const float* W3; const float* B3; const float* G3; const float* E3;
  const float* w4; const float* b4;
  float* out;
  float* ws;
};

// Monotone-counter grid barrier: 256 blocks, guaranteed co-resident
// (grid == CU count, 1 block/CU min capacity; LDS 32KB -> 4 blocks/CU cap).
// Counter zeroed by a memset node before the kernel each launch.
__device__ inline void gbar(unsigned* bar, unsigned target) {
  __syncthreads();
  if (threadIdx.x == 0) {
    __hip_atomic_fetch_add(bar, 1u, __ATOMIC_SEQ_CST, __HIP_MEMORY_SCOPE_AGENT);
    while (__hip_atomic_load(bar, __ATOMIC_SEQ_CST, __HIP_MEMORY_SCOPE_AGENT) <
           target) {
      __builtin_amdgcn_s_sleep(1);
    }
  }
  __syncthreads();
}

__global__ __launch_bounds__(256) void mega(Params p) {
  const int blk = blockIdx.x;
  const int tid = threadIdx.x;
  float* ws = p.ws;
  unsigned* bar = (unsigned*)ws + BAR_OFF;

  __shared__ union {
    struct { float4 pt[NP]; float wsum[4]; } a;       // scan + misc
    struct { float dT[16 * 504]; float corrp[16]; } c; // corr: dT[c][j]
    struct { float part[4][64]; } l;                   // layers
  } sm;
  __shared__ int lcnt;

  // ---------------- phase A: pair scan + per-batch misc -------------------
  {
    const int b = blk >> 2;
    const int st = blk & 3;
    if (tid == 0) lcnt = 0;
    const float* xr = p.xyz + b * 1500;
    for (int idx = tid; idx < NP; idx += 256) {
      float x = xr[idx], y = xr[500 + idx], z = xr[1000 + idx];
      sm.a.pt[idx] = make_float4(x, y, z, x * x + y * y + z * z);
    }
    __syncthreads();

    const int j0 = st * JSEG, j1 = j0 + JSEG;
    const int i0 = tid, i1 = tid + 256;
    float4 p0 = sm.a.pt[i0];
    float4 p1 = (i1 < NP) ? sm.a.pt[i1] : make_float4(0.f, 0.f, 0.f, 0.f);
    int* eseg = (int*)ws + EDGE_OFF + (b * SEGS + st) * CAPE;

    for (int j = j0; j < j1; ++j) {
      float4 q = sm.a.pt[j];  // wave-uniform -> LDS broadcast
      if (i0 < j) {
        float dot = p0.x * q.x + p0.y * q.y + p0.z * q.z;
        float d = sqrtf(fabsf(p0.w + q.w - 2.f * dot));
        if (d > 0.19f && d < 0.21f) {
          int e = atomicAdd(&lcnt, 1);
          if (e < CAPE) eseg[e] = (i0 << 16) | j;
        }
      }
      if (i1 < j) {
        float dot = p1.x * q.x + p1.y * q.y + p1.z * q.z;
        float d = sqrtf(fabsf(p1.w + q.w - 2.f * dot));
        if (d > 0.19f && d < 0.21f) {
          int e = atomicAdd(&lcnt, 1);
          if (e < CAPE) eseg[e] = (i1 << 16) | j;
        }
      }
    }
    __syncthreads();
    if (tid == 0)
      ((int*)ws)[CNT_OFF + b * SEGS + st] = lcnt < CAPE ? lcnt : CAPE;

    if (blk < NB) {  // misc for batch blk
      const int b2 = blk;
      float s = 0.f;
      for (int i = tid; i < NP; i += 256) s += p.temp[b2 * NP + i];
      for (int off = 32; off; off >>= 1) s += __shfl_xor(s, off);
      if ((tid & 63) == 0) sm.a.wsum[tid >> 6] = s;
      __syncthreads();
      if (tid == 0)
        p.out[64 + b2] = (sm.a.wsum[0] + sm.a.wsum[1] + sm.a.wsum[2] +
                          sm.a.wsum[3]) * (1.f / 500.f);
      if (tid < 128) ws[CT_OFF + (128 + tid) * 64 + b2] = p.l3[b2 * NC + tid];
      if (tid == 0) p.out[b2] = p.b4[0];  // tc = bias; layer-3 atomicAdds
    }
  }
  gbar(bar, 256);

  // -------- phase B: correlation (2 chan-groups/block) + fused copy -------
  {
    const int b = blk >> 2;
    for (int pass = 0; pass < 2; ++pass) {
      const int u = 2 * blk + pass;      // unit: same b, chan-group u&7
      const int c0 = (u & 7) * 16;
      if (tid < 16) sm.c.corrp[tid] = 0.f;

      const float4* in4 = (const float4*)p.data + b * 16000 + c0 * 125;
      float4* out4 = (float4*)(p.out + OUT_PTS_OFF) + b * 16000 + c0 * 125;
      for (int idx = tid; idx < 2000; idx += 256) {
        float4 v = in4[idx];
        out4[idx] = v;                          // pass-through copy, fused
        int c = idx / 125;                      // channel 0..15
        int j4 = idx - c * 125;
        *(float4*)(&sm.c.dT[c * 504 + 4 * j4]) = v;  // contiguous b128 write
      }
      __syncthreads();

      const int quad = tid & 3;   // 4-channel group
      const int slot = tid >> 2;  // 64 edge slots
      float a0 = 0.f, a1 = 0.f, a2 = 0.f, a3 = 0.f;
      const int* cnts = (const int*)ws + CNT_OFF + b * SEGS;
      int Etot = 0;
      const float* Cb = sm.c.dT + (quad * 4) * 504;
      for (int seg = 0; seg < SEGS; ++seg) {
        int E = cnts[seg];
        Etot += E;
        const int* eseg = (const int*)ws + EDGE_OFF + (b * SEGS + seg) * CAPE;
        for (int e = slot; e < E; e += 64) {
          int ij = eseg[e];
          int i = ij >> 16, j = ij & 0xffff;
          a0 += Cb[i] * Cb[j];
          a1 += Cb[504 + i] * Cb[504 + j];
          a2 += Cb[1008 + i] * Cb[1008 + j];
          a3 += Cb[1512 + i] * Cb[1512 + j];
        }
      }
      for (int off = 4; off < 64; off <<= 1) {
        a0 += __shfl_xor(a0, off);
        a1 += __shfl_xor(a1, off);
        a2 += __shfl_xor(a2, off);
        a3 += __shfl_xor(a3, off);
      }
      if ((tid & 63) < 4) {  // one representative per quad per wave
        atomicAdd(&sm.c.corrp[quad * 4 + 0], a0);
        atomicAdd(&sm.c.corrp[quad * 4 + 1], a1);
        atomicAdd(&sm.c.corrp[quad * 4 + 2], a2);
        atomicAdd(&sm.c.corrp[quad * 4 + 3], a3);
      }
      __syncthreads();
      if (tid < 16) {
        // mask symmetric: ordered count = 2E, ordered sum = 2 * upper sum
        float denom = fmaxf(2.f * (float)Etot, 1.f);
        float v = 2.f * sm.c.corrp[tid] / denom;
        p.out[OUT_CORR_OFF + b * NC + c0 + tid] = v;
        ws[CT_OFF + (c0 + tid) * 64 + b] = v;
      }
      __syncthreads();  // protect dT/corrp before next pass restages
    }
  }
  gbar(bar, 512);

  // ---------------- phases C-F: 4 MLP layers, one feature/block -----------
  float* cT = ws + CT_OFF;
  float* hA = ws + H1_OFF;
  float* hB = ws + H2_OFF;
  const float* Wl[4] = {p.W0, p.W1, p.W2, p.W3};
  const float* Bl[4] = {p.B0, p.B1, p.B2, p.B3};
  const float* Gl[4] = {p.G0, p.G1, p.G2, p.G3};
  const float* El[4] = {p.E0, p.E1, p.E2, p.E3};
  const float* xs[4] = {cT, hA, hB, hA};
  float* ys[4] = {hA, hB, hA, nullptr};

  for (int l = 0; l < 4; ++l) {
    const int o = blk;
    const int b = tid & 63;
    const int w = tid >> 6;
    const float* wr = Wl[l] + o * NH + w * 64;
    const float* xp = xs[l] + (w * 64) * 64 + b;
    float acc = 0.f;
#pragma unroll
    for (int i = 0; i < 64; ++i) acc += xp[i * 64] * wr[i];
    sm.l.part[w][b] = acc;
    __syncthreads();
    if (w == 0) {
      float t = sm.l.part[0][b] + sm.l.part[1][b] + sm.l.part[2][b] +
                sm.l.part[3][b] + Bl[l][o];
      float s1 = t;
      for (int off = 32; off; off >>= 1) s1 += __shfl_xor(s1, off);
      float m = s1 * (1.f / 64.f);
      float d = t - m;
      float s2 = d * d;
      for (int off = 32; off; off >>= 1) s2 += __shfl_xor(s2, off);
      float var = s2 * (1.f / 64.f);
      float h = Gl[l][o] * d * rsqrtf(var + EPS_BN) + El[l][o];
      h = fmaxf(h, 0.f);
      if (l == 3) {
        atomicAdd(&p.out[b], p.w4[o] * h);
      } else {
        ys[l][o * 64 + b] = h;
      }
    }
    if (l < 3) gbar(bar, 768 + l * 256);
  }
}

extern "C" void kernel_launch(void* const* d_in, const int* in_sizes, int n_in,
                              void* d_out, int out_size, void* d_ws,
                              size_t ws_size, hipStream_t stream) {
  Params p;
  p.xyz = (const float*)d_in[0];
  p.data = (const float*)d_in[1];
  p.l3 = (const float*)d_in[2];
  p.temp = (const float*)d_in[3];
  p.W0 = (const float*)d_in[4];  p.B0 = (const float*)d_in[5];
  p.G0 = (const float*)d_in[6];  p.E0 = (const float*)d_in[7];
  p.W1 = (const float*)d_in[8];  p.B1 = (const float*)d_in[9];
  p.G1 = (const float*)d_in[10]; p.E1 = (const float*)d_in[11];
  p.W2 = (const float*)d_in[12]; p.B2 = (const float*)d_in[13];
  p.G2 = (const float*)d_in[14]; p.E2 = (const float*)d_in[15];
  p.W3 = (const float*)d_in[16]; p.B3 = (const float*)d_in[17];
  p.G3 = (const float*)d_in[18]; p.E3 = (const float*)d_in[19];
  p.w4 = (const float*)d_in[20]; p.b4 = (const float*)d_in[21];
  p.out = (float*)d_out;
  p.ws = (float*)d_ws;

  // zero the barrier counter (ws is poisoned 0xAA before every launch)
  hipMemsetAsync((char*)d_ws + BAR_OFF * sizeof(float), 0, sizeof(unsigned),
                 stream);
  mega<<<256, 256, 0, stream>>>(p);
}